// Round 2
// baseline (260.416 us; speedup 1.0000x reference)
//
#include <hip/hip_runtime.h>

#define HH 128
#define WW 128
#define CIN 256
#define COUT 256
#define KTOT 2304   // 9 * 256, k = kk*256 + ci
#define BM 128
#define BN 128
#define BK 64
#define LDA (BK + 8) // 72 elements * 2B = 144B row stride: 16B aligned, bank-shift 4
#define HW (HH * WW)

typedef __attribute__((ext_vector_type(8))) short short8;
typedef __attribute__((ext_vector_type(4))) float f32x4;

__device__ __forceinline__ unsigned rne_bf16(float f) {
  unsigned u = __float_as_uint(f);
  return (u + 0x7FFFu + ((u >> 16) & 1u)) >> 16;
}
__device__ __forceinline__ unsigned pack_bf16x2(float lo, float hi) {
  return rne_bf16(lo) | (rne_bf16(hi) << 16);
}
__device__ __forceinline__ float bflo(unsigned u) { return __uint_as_float(u << 16); }
__device__ __forceinline__ float bfhi(unsigned u) { return __uint_as_float(u & 0xFFFF0000u); }

__device__ __forceinline__ unsigned blend2(unsigned a, unsigned b, unsigned c, unsigned d,
                                           float w00, float w01, float w10, float w11) {
  float lo = w00 * bflo(a) + w01 * bflo(b) + w10 * bflo(c) + w11 * bflo(d);
  float hi = w00 * bfhi(a) + w01 * bfhi(b) + w10 * bfhi(c) + w11 * bfhi(d);
  return pack_bf16x2(lo, hi);
}

// x [N][CIN][H][W] fp32 -> xt [N][H][W][CIN] bf16.  One block per (n,h) row.
__global__ void transpose_x(const float* __restrict__ x, unsigned short* __restrict__ xt) {
  int b = blockIdx.x;
  int n = b >> 7, h = b & 127;
  __shared__ float tile[64][129];
  const float* xp = x + ((size_t)n * CIN * HH + h) * WW; // xp[ci*HW + w]
  for (int c0 = 0; c0 < CIN; c0 += 64) {
    for (int e = threadIdx.x; e < 64 * 128; e += 256) {
      int w = e & 127, ci = e >> 7;
      tile[ci][w] = xp[(size_t)(c0 + ci) * HW + w];
    }
    __syncthreads();
    // write: element pair (w, 2cp..2cp+1) -> 4B coalesced along ci
    unsigned* dst = (unsigned*)(xt + ((size_t)(n * HH + h) * WW) * CIN + c0);
    for (int e = threadIdx.x; e < 128 * 32; e += 256) {
      int w = e >> 5, cp = e & 31;
      dst[w * (CIN / 2) + cp] = pack_bf16x2(tile[2 * cp][w], tile[2 * cp + 1][w]);
    }
    __syncthreads();
  }
}

// weight [COUT][CIN][3][3] fp32 -> wT [COUT][kk*256+ci] bf16
__global__ void transform_w(const float* __restrict__ wsrc, unsigned short* __restrict__ wT) {
  int o = blockIdx.x * 256 + threadIdx.x;
  if (o >= COUT * KTOT) return;
  int co = o / KTOT;
  int r = o - co * KTOT;
  int kk = r >> 8, ci = r & 255;
  wT[o] = rne_bf16(wsrc[(size_t)(co * CIN + ci) * 9 + kk]);
}

// One block: 128 pixels (one image row) x 128 couts. 4 waves, 4x4 16x16x32 MFMA tiles each.
__global__ __launch_bounds__(256, 2) void fused_deform_gemm(
    const float* __restrict__ obb, const unsigned short* __restrict__ xt,
    const unsigned short* __restrict__ wT, float* __restrict__ out,
    const int* __restrict__ stride_p) {
  int bm = blockIdx.x; // 0..255 -> (n,h)
  int bn = blockIdx.y; // 0..1   -> cout half
  int n = bm >> 7, h = bm & 127;
  int tid = threadIdx.x;

  __shared__ unsigned short Alds[BM][LDA];
  __shared__ unsigned short Blds[BN][LDA];
  __shared__ float pcx[128], pcy[128], pA[128], pB[128], pC[128], pD[128];

  float inv_s = 1.0f / (float)stride_p[0];

  if (tid < 128) {
    int w = tid;
    const float* op = obb + ((size_t)n * 5 * HH + h) * WW + w; // op[c*HW]
    float xc = op[0] * inv_s;
    float yc = op[(size_t)1 * HW] * inv_s;
    float bw = op[(size_t)2 * HW] * inv_s;
    float bh = op[(size_t)3 * HW] * inv_s;
    float th = op[(size_t)4 * HW];
    float sn, cs;
    sincosf(th, &sn, &cs);
    float dw = bw * (1.0f / 3.0f), dh = bh * (1.0f / 3.0f);
    pcx[w] = xc; pcy[w] = yc;
    pA[w] = dw * cs; pB[w] = dh * sn;
    pC[w] = dw * sn; pD[w] = dh * cs;
  }

  f32x4 acc[4][4] = {};

  int lane = tid & 63;
  int wv = tid >> 6;
  int wm = (wv >> 1) * 64, wn = (wv & 1) * 64;
  int l15 = lane & 15, l4 = lane >> 4;
  int p = tid >> 1;          // pixel handled in A-build
  int halfsel = tid & 1;     // which 32-channel half

  __syncthreads();

  for (int it = 0; it < KTOT / BK; ++it) {
    int kk = it >> 2;
    int c0 = (it & 3) << 6;
    int ky = kk / 3 - 1;
    int kx = kk - (kk / 3) * 3 - 1;

    // ---- A-tile build: bilinear sample 64 channels of tap kk for 128 pixels ----
    {
      float sx = pcx[p] + (float)kx * pA[p] - (float)ky * pB[p];
      float sy = pcy[p] + (float)kx * pC[p] + (float)ky * pD[p];
      float fx = floorf(sx), fy = floorf(sy);
      float lx = sx - fx, ly = sy - fy;
      int x0 = (int)fx, y0 = (int)fy;
      float vy0 = (y0 >= 0 && y0 < HH) ? 1.0f : 0.0f;
      float vy1 = (y0 >= -1 && y0 < HH - 1) ? 1.0f : 0.0f;
      float vx0 = (x0 >= 0 && x0 < WW) ? 1.0f : 0.0f;
      float vx1 = (x0 >= -1 && x0 < WW - 1) ? 1.0f : 0.0f;
      float w00 = (1.0f - ly) * (1.0f - lx) * vy0 * vx0;
      float w01 = (1.0f - ly) * lx * vy0 * vx1;
      float w10 = ly * (1.0f - lx) * vy1 * vx0;
      float w11 = ly * lx * vy1 * vx1;
      int xc0 = min(max(x0, 0), WW - 1), xc1 = min(max(x0 + 1, 0), WW - 1);
      int yc0 = min(max(y0, 0), HH - 1), yc1 = min(max(y0 + 1, 0), HH - 1);
      int coff = c0 + (halfsel << 5);   // global channel offset within the 256-ch group
      const uint4* p00 = (const uint4*)(xt + ((size_t)((n * HH + yc0) * WW + xc0)) * CIN + coff);
      const uint4* p01 = (const uint4*)(xt + ((size_t)((n * HH + yc0) * WW + xc1)) * CIN + coff);
      const uint4* p10 = (const uint4*)(xt + ((size_t)((n * HH + yc1) * WW + xc0)) * CIN + coff);
      const uint4* p11 = (const uint4*)(xt + ((size_t)((n * HH + yc1) * WW + xc1)) * CIN + coff);
      // FIX (R1): LDS column is LOCAL position within BK (0..63), not the global
      // channel offset c0+...  Previous version wrote up to column 224 -> OOB/corruption.
      uint4* dstq = (uint4*)(&Alds[p][halfsel << 5]);
#pragma unroll
      for (int q = 0; q < 4; ++q) {
        uint4 a = p00[q], b = p01[q], c = p10[q], d = p11[q];
        uint4 r;
        r.x = blend2(a.x, b.x, c.x, d.x, w00, w01, w10, w11);
        r.y = blend2(a.y, b.y, c.y, d.y, w00, w01, w10, w11);
        r.z = blend2(a.z, b.z, c.z, d.z, w00, w01, w10, w11);
        r.w = blend2(a.w, b.w, c.w, d.w, w00, w01, w10, w11);
        dstq[q] = r;
      }
    }

    // ---- B-tile stage: wT[bn*128 + row][k0 .. k0+63] ----
    {
      int k0 = it << 6;
#pragma unroll
      for (int r2 = 0; r2 < 4; ++r2) {
        int idx = r2 * 256 + tid;
        int row = idx >> 3, kc = (idx & 7) << 3;
        const uint4* src = (const uint4*)(wT + (size_t)(bn * BN + row) * KTOT + k0 + kc);
        *(uint4*)(&Blds[row][kc]) = *src;
      }
    }
    __syncthreads();

    // ---- MFMA ----
#pragma unroll
    for (int ks = 0; ks < BK; ks += 32) {
      short8 af[4], bf[4];
#pragma unroll
      for (int i = 0; i < 4; ++i)
        af[i] = *(const short8*)(&Alds[wm + i * 16 + l15][ks + l4 * 8]);
#pragma unroll
      for (int j = 0; j < 4; ++j)
        bf[j] = *(const short8*)(&Blds[wn + j * 16 + l15][ks + l4 * 8]);
#pragma unroll
      for (int i = 0; i < 4; ++i)
#pragma unroll
        for (int j = 0; j < 4; ++j)
          acc[i][j] = __builtin_amdgcn_mfma_f32_16x16x32_bf16(af[i], bf[j], acc[i][j], 0, 0, 0);
    }
    __syncthreads();
  }

  // ---- epilogue: out[n][co][h][w], float4 along w ----
  float* outp = out + (size_t)n * COUT * HW + (size_t)h * WW;
#pragma unroll
  for (int i = 0; i < 4; ++i) {
    int w0 = wm + i * 16 + l4 * 4;
#pragma unroll
    for (int j = 0; j < 4; ++j) {
      int co = bn * BN + wn + j * 16 + l15;
      *(f32x4*)(outp + (size_t)co * HW + w0) = acc[i][j];
    }
  }
}

extern "C" void kernel_launch(void* const* d_in, const int* in_sizes, int n_in,
                              void* d_out, int out_size, void* d_ws, size_t ws_size,
                              hipStream_t stream) {
  const float* x = (const float*)d_in[0];
  const float* obb = (const float*)d_in[1];
  const float* wgt = (const float*)d_in[2];
  const int* stridep = (const int*)d_in[3];
  float* out = (float*)d_out;

  unsigned short* xt = (unsigned short*)d_ws;                 // 2*128*128*256 bf16 = 16.8 MB
  unsigned short* wT = xt + (size_t)2 * HH * WW * CIN;        // 256*2304 bf16 = 1.2 MB

  transpose_x<<<dim3(2 * HH), 256, 0, stream>>>(x, xt);
  transform_w<<<dim3((COUT * KTOT + 255) / 256), 256, 0, stream>>>(wgt, wT);
  fused_deform_gemm<<<dim3(2 * HH, 2), 256, 0, stream>>>(obb, xt, wT, out, stridep);
}

// Round 3
// 238.243 us; speedup vs baseline: 1.0931x; 1.0931x over previous
//
#include <hip/hip_runtime.h>

#define HH 128
#define WW 128
#define CIN 256
#define COUT 256
#define KTOT 2304   // 9 * 256, k = kk*256 + ci
#define BM 128
#define BN 128
#define BK 64
#define LDA (BK + 8) // 72 elements * 2B = 144B row stride
#define HW (HH * WW)
#define NIT 36       // 9 taps * 4 channel-chunks

typedef __attribute__((ext_vector_type(8))) short short8;
typedef __attribute__((ext_vector_type(4))) float f32x4;

__device__ __forceinline__ unsigned rne_bf16(float f) {
  unsigned u = __float_as_uint(f);
  return (u + 0x7FFFu + ((u >> 16) & 1u)) >> 16;
}
__device__ __forceinline__ unsigned pack_bf16x2(float lo, float hi) {
  return rne_bf16(lo) | (rne_bf16(hi) << 16);
}
__device__ __forceinline__ float bflo(unsigned u) { return __uint_as_float(u << 16); }
__device__ __forceinline__ float bfhi(unsigned u) { return __uint_as_float(u & 0xFFFF0000u); }

__device__ __forceinline__ unsigned blend2(unsigned a, unsigned b, unsigned c, unsigned d,
                                           float w00, float w01, float w10, float w11) {
  float lo = w00 * bflo(a) + w01 * bflo(b) + w10 * bflo(c) + w11 * bflo(d);
  float hi = w00 * bfhi(a) + w01 * bfhi(b) + w10 * bfhi(c) + w11 * bfhi(d);
  return pack_bf16x2(lo, hi);
}

// x [N][CIN][H][W] fp32 -> xt [N][H][W][CIN] bf16.  One block per (n,h) row.
__global__ void transpose_x(const float* __restrict__ x, unsigned short* __restrict__ xt) {
  int b = blockIdx.x;
  int n = b >> 7, h = b & 127;
  __shared__ float tile[64][129];
  const float* xp = x + ((size_t)n * CIN * HH + h) * WW;
  for (int c0 = 0; c0 < CIN; c0 += 64) {
    for (int e = threadIdx.x; e < 64 * 128; e += 256) {
      int w = e & 127, ci = e >> 7;
      tile[ci][w] = xp[(size_t)(c0 + ci) * HW + w];
    }
    __syncthreads();
    unsigned* dst = (unsigned*)(xt + ((size_t)(n * HH + h) * WW) * CIN + c0);
    for (int e = threadIdx.x; e < 128 * 32; e += 256) {
      int w = e >> 5, cp = e & 31;
      dst[w * (CIN / 2) + cp] = pack_bf16x2(tile[2 * cp][w], tile[2 * cp + 1][w]);
    }
    __syncthreads();
  }
}

// weight [COUT][CIN][3][3] fp32 -> wT [COUT][kk*256+ci] bf16
__global__ void transform_w(const float* __restrict__ wsrc, unsigned short* __restrict__ wT) {
  int o = blockIdx.x * 256 + threadIdx.x;
  if (o >= COUT * KTOT) return;
  int co = o / KTOT;
  int r = o - co * KTOT;
  int kk = r >> 8, ci = r & 255;
  wT[o] = rne_bf16(wsrc[(size_t)(co * CIN + ci) * 9 + kk]);
}

// One block: 128 pixels (one image row) x 128 couts. 4 waves, 4x4 16x16x32 MFMA tiles.
// R2: XCD-swizzled block mapping, full-line gather lanes, reg-prefetch pipeline.
__global__ __launch_bounds__(256, 2) void fused_deform_gemm(
    const float* __restrict__ obb, const unsigned short* __restrict__ xt,
    const unsigned short* __restrict__ wT, float* __restrict__ out,
    const int* __restrict__ stride_p) {
  // XCD swizzle: g%8 = XCD (HW round-robin heuristic). Each XCD gets a
  // contiguous 32-row band, both bn halves -> ~2.6MB working set in its 4MB L2.
  int g = blockIdx.x;
  int xcd = g & 7, li = g >> 3;
  int bm = xcd * 32 + (li >> 1); // 0..255 -> (n,h)
  int bn = li & 1;               // cout half
  int n = bm >> 7, h = bm & 127;
  int tid = threadIdx.x;

  __shared__ unsigned short Alds[BM][LDA];
  __shared__ unsigned short Blds[BN][LDA];
  __shared__ float pcx[128], pcy[128], pA[128], pB[128], pC[128], pD[128];

  float inv_s = 1.0f / (float)stride_p[0];

  if (tid < 128) {
    int w = tid;
    const float* op = obb + ((size_t)n * 5 * HH + h) * WW + w;
    float xc = op[0] * inv_s;
    float yc = op[(size_t)1 * HW] * inv_s;
    float bw = op[(size_t)2 * HW] * inv_s;
    float bh = op[(size_t)3 * HW] * inv_s;
    float th = op[(size_t)4 * HW];
    float sn, cs;
    sincosf(th, &sn, &cs);
    float dw = bw * (1.0f / 3.0f), dh = bh * (1.0f / 3.0f);
    pcx[w] = xc; pcy[w] = yc;
    pA[w] = dw * cs; pB[w] = dh * sn;
    pC[w] = dw * sn; pD[w] = dh * cs;
  }

  f32x4 acc[4][4] = {};

  int lane = tid & 63;
  int wv = tid >> 6;
  int wm = (wv >> 1) * 64, wn = (wv & 1) * 64;
  int l15 = lane & 15, l4 = lane >> 4;

  // A-build lane map: 8 lanes per pixel, each lane owns one 16B chunk of the
  // 128B (64-channel) region -> one full cache line per 8 lanes per instr.
  int chunk8 = (lane & 7) * 8;     // element offset of this lane's 16B chunk
  int prow = wv * 32 + (lane >> 3); // + 8*j = pixel index

  // B staging constants per thread (4 rows of 8 k-elems each)
  size_t wTrow[4];
  unsigned short* Bp[4];
  int Arow[4]; // pixel per job j (filled in prep loop via prow + 8j)
#pragma unroll
  for (int r2 = 0; r2 < 4; ++r2) {
    int idx = r2 * 256 + tid;
    int row = idx >> 3, kc = (idx & 7) << 3;
    wTrow[r2] = (size_t)(bn * BN + row) * KTOT + kc;
    Bp[r2] = &Blds[row][kc];
  }

  // Per-tap state (registers, live across the 4 channel-chunks of a tap)
  float wgt_[4][4]; // w00,w01,w10,w11 per job
  int boff[4][4];   // corner base element offsets per job
  uint4 pf[4][4];   // prefetched corner data  (job, corner)
  uint4 pfB[4];     // prefetched B tile

  __syncthreads(); // params ready

  auto prep = [&](int kk) {
    float fky = (float)(kk / 3 - 1);
    float fkx = (float)(kk % 3 - 1);
#pragma unroll
    for (int j = 0; j < 4; ++j) {
      int p = prow + 8 * j;
      Arow[j] = p;
      float sx = pcx[p] + fkx * pA[p] - fky * pB[p];
      float sy = pcy[p] + fkx * pC[p] + fky * pD[p];
      float fx = floorf(sx), fy = floorf(sy);
      float lx = sx - fx, ly = sy - fy;
      int x0 = (int)fx, y0 = (int)fy;
      float vy0 = (y0 >= 0 && y0 < HH) ? 1.0f : 0.0f;
      float vy1 = (y0 >= -1 && y0 < HH - 1) ? 1.0f : 0.0f;
      float vx0 = (x0 >= 0 && x0 < WW) ? 1.0f : 0.0f;
      float vx1 = (x0 >= -1 && x0 < WW - 1) ? 1.0f : 0.0f;
      wgt_[j][0] = (1.0f - ly) * (1.0f - lx) * vy0 * vx0;
      wgt_[j][1] = (1.0f - ly) * lx * vy0 * vx1;
      wgt_[j][2] = ly * (1.0f - lx) * vy1 * vx0;
      wgt_[j][3] = ly * lx * vy1 * vx1;
      int xc0 = min(max(x0, 0), WW - 1), xc1 = min(max(x0 + 1, 0), WW - 1);
      int yc0 = min(max(y0, 0), HH - 1), yc1 = min(max(y0 + 1, 0), HH - 1);
      int rb0 = (n * HH + yc0) * WW, rb1 = (n * HH + yc1) * WW;
      boff[j][0] = (rb0 + xc0) * CIN;
      boff[j][1] = (rb0 + xc1) * CIN;
      boff[j][2] = (rb1 + xc0) * CIN;
      boff[j][3] = (rb1 + xc1) * CIN;
    }
  };

  auto issueA = [&](int cc) {
    int co = cc * 64 + chunk8;
#pragma unroll
    for (int j = 0; j < 4; ++j)
#pragma unroll
      for (int c = 0; c < 4; ++c)
        pf[j][c] = *(const uint4*)(xt + boff[j][c] + co);
  };

  auto issueB = [&](int it) {
    size_t k0 = (size_t)it * 64;
#pragma unroll
    for (int r2 = 0; r2 < 4; ++r2)
      pfB[r2] = *(const uint4*)(wT + wTrow[r2] + k0);
  };

  prep(0);
  issueA(0);
  issueB(0);

  for (int it = 0; it < NIT; ++it) {
    // ---- blend prefetched corners -> Alds; store prefetched B -> Blds ----
#pragma unroll
    for (int j = 0; j < 4; ++j) {
      uint4 r;
      r.x = blend2(pf[j][0].x, pf[j][1].x, pf[j][2].x, pf[j][3].x,
                   wgt_[j][0], wgt_[j][1], wgt_[j][2], wgt_[j][3]);
      r.y = blend2(pf[j][0].y, pf[j][1].y, pf[j][2].y, pf[j][3].y,
                   wgt_[j][0], wgt_[j][1], wgt_[j][2], wgt_[j][3]);
      r.z = blend2(pf[j][0].z, pf[j][1].z, pf[j][2].z, pf[j][3].z,
                   wgt_[j][0], wgt_[j][1], wgt_[j][2], wgt_[j][3]);
      r.w = blend2(pf[j][0].w, pf[j][1].w, pf[j][2].w, pf[j][3].w,
                   wgt_[j][0], wgt_[j][1], wgt_[j][2], wgt_[j][3]);
      *(uint4*)(&Alds[Arow[j]][chunk8]) = r;
    }
#pragma unroll
    for (int r2 = 0; r2 < 4; ++r2)
      *(uint4*)Bp[r2] = pfB[r2];
    __syncthreads();

    // ---- prefetch next iteration (flies during MFMA below) ----
    int nx = it + 1;
    if (nx < NIT) {
      if ((nx & 3) == 0) prep(nx >> 2);
      issueA(nx & 3);
      issueB(nx);
    }

    // ---- MFMA ----
#pragma unroll
    for (int ks = 0; ks < BK; ks += 32) {
      short8 af[4], bf[4];
#pragma unroll
      for (int i = 0; i < 4; ++i)
        af[i] = *(const short8*)(&Alds[wm + i * 16 + l15][ks + l4 * 8]);
#pragma unroll
      for (int j = 0; j < 4; ++j)
        bf[j] = *(const short8*)(&Blds[wn + j * 16 + l15][ks + l4 * 8]);
#pragma unroll
      for (int i = 0; i < 4; ++i)
#pragma unroll
        for (int j = 0; j < 4; ++j)
          acc[i][j] = __builtin_amdgcn_mfma_f32_16x16x32_bf16(af[i], bf[j], acc[i][j], 0, 0, 0);
    }
    __syncthreads();
  }

  // ---- epilogue: out[n][co][h][w], float4 along w ----
  float* outp = out + (size_t)n * COUT * HW + (size_t)h * WW;
#pragma unroll
  for (int i = 0; i < 4; ++i) {
    int w0 = wm + i * 16 + l4 * 4;
#pragma unroll
    for (int j = 0; j < 4; ++j) {
      int co = bn * BN + wn + j * 16 + l15;
      *(f32x4*)(outp + (size_t)co * HW + w0) = acc[i][j];
    }
  }
}

extern "C" void kernel_launch(void* const* d_in, const int* in_sizes, int n_in,
                              void* d_out, int out_size, void* d_ws, size_t ws_size,
                              hipStream_t stream) {
  const float* x = (const float*)d_in[0];
  const float* obb = (const float*)d_in[1];
  const float* wgt = (const float*)d_in[2];
  const int* stridep = (const int*)d_in[3];
  float* out = (float*)d_out;

  unsigned short* xt = (unsigned short*)d_ws;          // 2*128*128*256 bf16 = 16.8 MB
  unsigned short* wT = xt + (size_t)2 * HH * WW * CIN; // 256*2304 bf16 = 1.2 MB

  transpose_x<<<dim3(2 * HH), 256, 0, stream>>>(x, xt);
  transform_w<<<dim3((COUT * KTOT + 255) / 256), 256, 0, stream>>>(wgt, wT);
  fused_deform_gemm<<<dim3(2 * HH * 2), 256, 0, stream>>>(obb, xt, wT, out, stridep);
}

// Round 4
// 195.313 us; speedup vs baseline: 1.3333x; 1.2198x over previous
//
#include <hip/hip_runtime.h>

#define HH 128
#define WW 128
#define CIN 256
#define COUT 256
#define KTOT 2304   // 9 * 256, k = kk*256 + ci
#define BM 64
#define BN 128
#define BK 64
#define LDA (BK + 8) // 72 elements * 2B = 144B row stride
#define HW (HH * WW)
#define NIT 36       // 9 taps * 4 channel-chunks

typedef __attribute__((ext_vector_type(8))) short short8;
typedef __attribute__((ext_vector_type(4))) float f32x4;

__device__ __forceinline__ unsigned rne_bf16(float f) {
  unsigned u = __float_as_uint(f);
  return (u + 0x7FFFu + ((u >> 16) & 1u)) >> 16;
}
__device__ __forceinline__ unsigned pack_bf16x2(float lo, float hi) {
  return rne_bf16(lo) | (rne_bf16(hi) << 16);
}
__device__ __forceinline__ float bflo(unsigned u) { return __uint_as_float(u << 16); }
__device__ __forceinline__ float bfhi(unsigned u) { return __uint_as_float(u & 0xFFFF0000u); }

__device__ __forceinline__ unsigned blend2(unsigned a, unsigned b, unsigned c, unsigned d,
                                           float w00, float w01, float w10, float w11) {
  float lo = w00 * bflo(a) + w01 * bflo(b) + w10 * bflo(c) + w11 * bflo(d);
  float hi = w00 * bfhi(a) + w01 * bfhi(b) + w10 * bfhi(c) + w11 * bfhi(d);
  return pack_bf16x2(lo, hi);
}

// x [N][CIN][H][W] fp32 -> xt [N][H][W][CIN] bf16.
// R4: one block per (n,h,64-channel group) -> 1024 blocks (was 256).
__global__ void transpose_x(const float* __restrict__ x, unsigned short* __restrict__ xt) {
  int b = blockIdx.x;
  int cg = b & 3;
  int nh = b >> 2;
  int n = nh >> 7, h = nh & 127;
  int c0 = cg << 6;
  __shared__ float tile[64][129];
  const float* xp = x + ((size_t)n * CIN * HH + h) * WW;
  for (int e = threadIdx.x; e < 64 * 128; e += 256) {
    int w = e & 127, ci = e >> 7;
    tile[ci][w] = xp[(size_t)(c0 + ci) * HW + w];
  }
  __syncthreads();
  unsigned* dst = (unsigned*)(xt + ((size_t)(n * HH + h) * WW) * CIN + c0);
  for (int e = threadIdx.x; e < 128 * 32; e += 256) {
    int w = e >> 5, cp = e & 31;
    dst[w * (CIN / 2) + cp] = pack_bf16x2(tile[2 * cp][w], tile[2 * cp + 1][w]);
  }
}

// weight [COUT][CIN][3][3] fp32 -> wT [COUT][kk*256+ci] bf16
__global__ void transform_w(const float* __restrict__ wsrc, unsigned short* __restrict__ wT) {
  int o = blockIdx.x * 256 + threadIdx.x;
  if (o >= COUT * KTOT) return;
  int co = o / KTOT;
  int r = o - co * KTOT;
  int kk = r >> 8, ci = r & 255;
  wT[o] = rne_bf16(wsrc[(size_t)(co * CIN + ci) * 9 + kk]);
}

// R4: BM=64 tiles -> 1024 blocks = 4 blocks/CU so independent blocks overlap
// their VALU-blend and MFMA phases on one CU (m114 co-scheduling).
// One block: 64 pixels (half an image row) x 128 couts. 4 waves, each 2x4
// 16x16x32 tiles (wave tile 32x64).
__global__ __launch_bounds__(256, 4) void fused_deform_gemm(
    const float* __restrict__ obb, const unsigned short* __restrict__ xt,
    const unsigned short* __restrict__ wT, float* __restrict__ out,
    const int* __restrict__ stride_p) {
  // XCD swizzle: g%8 = XCD. Each XCD gets a contiguous 32-row band
  // (all mh/bn variants) -> ~2.6MB xt working set in its 4MB L2.
  int g = blockIdx.x;
  int xcd = g & 7, li = g >> 3;
  int u = xcd * 128 + li;   // 0..1023
  int bn = u & 1;           // cout half
  int mh = (u >> 1) & 1;    // which half of the image row
  int bm = u >> 2;          // row id 0..255
  int n = bm >> 7, h = bm & 127;
  int tid = threadIdx.x;

  __shared__ unsigned short Alds[BM][LDA];
  __shared__ unsigned short Blds[BN][LDA];
  __shared__ float pcx[64], pcy[64], pA[64], pB[64], pC[64], pD[64];

  float inv_s = 1.0f / (float)stride_p[0];

  if (tid < 64) {
    int w = mh * 64 + tid;
    const float* op = obb + ((size_t)n * 5 * HH + h) * WW + w;
    float xc = op[0] * inv_s;
    float yc = op[(size_t)1 * HW] * inv_s;
    float bw = op[(size_t)2 * HW] * inv_s;
    float bh = op[(size_t)3 * HW] * inv_s;
    float th = op[(size_t)4 * HW];
    float sn, cs;
    sincosf(th, &sn, &cs);
    float dw = bw * (1.0f / 3.0f), dh = bh * (1.0f / 3.0f);
    pcx[tid] = xc; pcy[tid] = yc;
    pA[tid] = dw * cs; pB[tid] = dh * sn;
    pC[tid] = dw * sn; pD[tid] = dh * cs;
  }

  f32x4 acc[2][4] = {};

  int lane = tid & 63;
  int wv = tid >> 6;
  int wm = (wv >> 1) * 32, wn = (wv & 1) * 64;
  int l15 = lane & 15, l4 = lane >> 4;

  // A-build lane map: 8 lanes per pixel, each lane owns one 16B chunk of the
  // 128B (64-channel) region. 256 threads cover 32 pixels/pass -> 2 jobs.
  int chunk8 = (lane & 7) * 8;
  int prow = wv * 8 + (lane >> 3); // 0..31; pixel p = j*32 + prow

  // B staging constants (4 rows of 8 k-elems each per thread)
  int wTrow[4];
  int Boffs[4];
#pragma unroll
  for (int r2 = 0; r2 < 4; ++r2) {
    int idx = r2 * 256 + tid;
    int row = idx >> 3, kc = (idx & 7) << 3;
    wTrow[r2] = (bn * BN + row) * KTOT + kc;
    Boffs[r2] = row * LDA + kc;
  }
  unsigned short* Bbase = &Blds[0][0];

  float wgt_[2][4]; // w00,w01,w10,w11 per job
  int boff[2][4];   // corner base element offsets per job
  uint4 pf[2][4];   // prefetched corner data (job, corner)

  __syncthreads(); // params ready

  auto prep = [&](int kk) {
    float fky = (float)(kk / 3 - 1);
    float fkx = (float)(kk % 3 - 1);
#pragma unroll
    for (int j = 0; j < 2; ++j) {
      int p = j * 32 + prow;
      float sx = pcx[p] + fkx * pA[p] - fky * pB[p];
      float sy = pcy[p] + fkx * pC[p] + fky * pD[p];
      float fx = floorf(sx), fy = floorf(sy);
      float lx = sx - fx, ly = sy - fy;
      int x0 = (int)fx, y0 = (int)fy;
      float vy0 = (y0 >= 0 && y0 < HH) ? 1.0f : 0.0f;
      float vy1 = (y0 >= -1 && y0 < HH - 1) ? 1.0f : 0.0f;
      float vx0 = (x0 >= 0 && x0 < WW) ? 1.0f : 0.0f;
      float vx1 = (x0 >= -1 && x0 < WW - 1) ? 1.0f : 0.0f;
      wgt_[j][0] = (1.0f - ly) * (1.0f - lx) * vy0 * vx0;
      wgt_[j][1] = (1.0f - ly) * lx * vy0 * vx1;
      wgt_[j][2] = ly * (1.0f - lx) * vy1 * vx0;
      wgt_[j][3] = ly * lx * vy1 * vx1;
      int xc0 = min(max(x0, 0), WW - 1), xc1 = min(max(x0 + 1, 0), WW - 1);
      int yc0 = min(max(y0, 0), HH - 1), yc1 = min(max(y0 + 1, 0), HH - 1);
      int rb0 = (n * HH + yc0) * WW, rb1 = (n * HH + yc1) * WW;
      boff[j][0] = (rb0 + xc0) * CIN;
      boff[j][1] = (rb0 + xc1) * CIN;
      boff[j][2] = (rb1 + xc0) * CIN;
      boff[j][3] = (rb1 + xc1) * CIN;
    }
  };

  auto issueA = [&](int cc) {
    int co = cc * 64 + chunk8;
#pragma unroll
    for (int j = 0; j < 2; ++j)
#pragma unroll
      for (int c = 0; c < 4; ++c)
        pf[j][c] = *(const uint4*)(xt + boff[j][c] + co);
  };

  prep(0);
  issueA(0);

  for (int it = 0; it < NIT; ++it) {
    // ---- blend prefetched corners -> Alds; load+store B tile ----
#pragma unroll
    for (int r2 = 0; r2 < 4; ++r2)
      *(uint4*)(Bbase + Boffs[r2]) = *(const uint4*)(wT + wTrow[r2] + it * 64);
#pragma unroll
    for (int j = 0; j < 2; ++j) {
      uint4 r;
      r.x = blend2(pf[j][0].x, pf[j][1].x, pf[j][2].x, pf[j][3].x,
                   wgt_[j][0], wgt_[j][1], wgt_[j][2], wgt_[j][3]);
      r.y = blend2(pf[j][0].y, pf[j][1].y, pf[j][2].y, pf[j][3].y,
                   wgt_[j][0], wgt_[j][1], wgt_[j][2], wgt_[j][3]);
      r.z = blend2(pf[j][0].z, pf[j][1].z, pf[j][2].z, pf[j][3].z,
                   wgt_[j][0], wgt_[j][1], wgt_[j][2], wgt_[j][3]);
      r.w = blend2(pf[j][0].w, pf[j][1].w, pf[j][2].w, pf[j][3].w,
                   wgt_[j][0], wgt_[j][1], wgt_[j][2], wgt_[j][3]);
      *(uint4*)(&Alds[j * 32 + prow][chunk8]) = r;
    }
    __syncthreads();

    // ---- prefetch next iteration's A corners (fly during MFMA) ----
    int nx = it + 1;
    if (nx < NIT) {
      if ((nx & 3) == 0) prep(nx >> 2);
      issueA(nx & 3);
    }

    // ---- MFMA ----
#pragma unroll
    for (int ks = 0; ks < BK; ks += 32) {
      short8 af[2], bf[4];
#pragma unroll
      for (int i = 0; i < 2; ++i)
        af[i] = *(const short8*)(&Alds[wm + i * 16 + l15][ks + l4 * 8]);
#pragma unroll
      for (int j = 0; j < 4; ++j)
        bf[j] = *(const short8*)(&Blds[wn + j * 16 + l15][ks + l4 * 8]);
#pragma unroll
      for (int i = 0; i < 2; ++i)
#pragma unroll
        for (int j = 0; j < 4; ++j)
          acc[i][j] = __builtin_amdgcn_mfma_f32_16x16x32_bf16(af[i], bf[j], acc[i][j], 0, 0, 0);
    }
    __syncthreads();
  }

  // ---- epilogue: out[n][co][h][w], float4 along w ----
  float* outp = out + (size_t)n * COUT * HW + (size_t)h * WW + mh * 64;
#pragma unroll
  for (int i = 0; i < 2; ++i) {
    int w0 = wm + i * 16 + l4 * 4;
#pragma unroll
    for (int j = 0; j < 4; ++j) {
      int co = bn * BN + wn + j * 16 + l15;
      *(f32x4*)(outp + (size_t)co * HW + w0) = acc[i][j];
    }
  }
}

extern "C" void kernel_launch(void* const* d_in, const int* in_sizes, int n_in,
                              void* d_out, int out_size, void* d_ws, size_t ws_size,
                              hipStream_t stream) {
  const float* x = (const float*)d_in[0];
  const float* obb = (const float*)d_in[1];
  const float* wgt = (const float*)d_in[2];
  const int* stridep = (const int*)d_in[3];
  float* out = (float*)d_out;

  unsigned short* xt = (unsigned short*)d_ws;          // 2*128*128*256 bf16 = 16.8 MB
  unsigned short* wT = xt + (size_t)2 * HH * WW * CIN; // 256*2304 bf16 = 1.2 MB

  transpose_x<<<dim3(2 * HH * 4), 256, 0, stream>>>(x, xt);
  transform_w<<<dim3((COUT * KTOT + 255) / 256), 256, 0, stream>>>(wgt, wT);
  fused_deform_gemm<<<dim3(2 * HH * 2 * 2), 256, 0, stream>>>(obb, xt, wT, out, stridep);
}